// Round 1
// baseline (470.311 us; speedup 1.0000x reference)
//
#include <hip/hip_runtime.h>
#include <stdint.h>

// GLSTM: B=16, T=96, N=325, D=64, H=64.
// 5200 independent rows (b,n), each a 96-step recurrence.
// One block (256 thr) per 16-row group; weights live in registers as MFMA
// B-fragments; bf16 MFMA (fp32 acc) for the two per-step matmuls.

#define TT 96
#define NNROW 325
#define STEP_OFS 20800          // N*H = 325*64 floats per time step
#define HID_TOTAL 31948800      // B*T*N*H
#define HT_OFS 31948800
#define CT_OFS 32281600         // HT_OFS + B*N*H

typedef __attribute__((ext_vector_type(8))) short short8;
typedef __attribute__((ext_vector_type(4))) short short4v;
typedef __attribute__((ext_vector_type(4))) float f32x4;

#define A_STRIDE 200   // shorts per A-buffer row: [x(64)|os(64)|h(64)|pad(8)]
#define G_STRIDE 21    // floats per gate column (16 rows + 5 pad, odd => bank-clean)

__device__ __forceinline__ short f2bf(float f) {
    union { float f; uint32_t u; } v; v.f = f;
    uint32_t r = (v.u + 0x7FFFu + ((v.u >> 16) & 1u)) >> 16;
    return (short)(r & 0xFFFFu);
}
__device__ __forceinline__ float fsig(float x) {
    return 1.0f / (1.0f + __expf(-x));
}
__device__ __forceinline__ float ftanh_fast(float x) {
    // 1 - 2/(e^{2x}+1); robust at +/-inf of exp
    return 1.0f - 2.0f / (__expf(2.0f * x) + 1.0f);
}

__global__ __launch_bounds__(256, 2)
void glstm_kernel(const float* __restrict__ x,
                  const float* __restrict__ o_s,
                  const float* __restrict__ U_x,
                  const float* __restrict__ V_x,
                  const float* __restrict__ b_x,
                  const float* __restrict__ U_g,
                  const float* __restrict__ V_g,
                  const float* __restrict__ b_g,
                  float* __restrict__ out)
{
    __shared__ __align__(16) short Abuf[16 * A_STRIDE];   // 6.4 KB
    __shared__ __align__(16) float Gbuf[384 * G_STRIDE];  // 32.3 KB

    const int tid  = threadIdx.x;
    const int g    = blockIdx.x;      // row-group 0..324
    const int lane = tid & 63;
    const int w    = tid >> 6;        // wave 0..3
    const int q    = lane >> 4;       // quad 0..3 (k-group)
    const int ln   = lane & 15;       // n / m index within tile

    // ---------------- one-time: weight B-fragments into registers ----------
    // Gates W = [U_x; V_x] (128 x 256): wave w owns cols [w*64, w*64+63].
    // Gov   W = [U_g; V_g] (128 x 128): wave w owns cols [w*32, w*32+31].
    // B-frag layout (16x16x32): lane holds B[k = q*8 + j][n = ln].
    short8 frW[4][4];
    short8 frG[2][4];
    #pragma unroll
    for (int nt = 0; nt < 4; ++nt) {
        const int col = w * 64 + nt * 16 + ln;
        #pragma unroll
        for (int kb = 0; kb < 4; ++kb) {
            const float* Wp = (kb < 2) ? (U_x + (size_t)(kb * 32 + q * 8) * 256 + col)
                                       : (V_x + (size_t)((kb - 2) * 32 + q * 8) * 256 + col);
            short8 fr;
            #pragma unroll
            for (int j = 0; j < 8; ++j) fr[j] = f2bf(Wp[(size_t)j * 256]);
            frW[nt][kb] = fr;
        }
    }
    #pragma unroll
    for (int nt = 0; nt < 2; ++nt) {
        const int col = w * 32 + nt * 16 + ln;
        #pragma unroll
        for (int kb = 0; kb < 4; ++kb) {
            const float* Wp = (kb < 2) ? (U_g + (size_t)(kb * 32 + q * 8) * 128 + col)
                                       : (V_g + (size_t)((kb - 2) * 32 + q * 8) * 128 + col);
            short8 fr;
            #pragma unroll
            for (int j = 0; j < 8; ++j) fr[j] = f2bf(Wp[(size_t)j * 128]);
            frG[nt][kb] = fr;
        }
    }

    // ---------------- staging thread mapping (x / o_s -> LDS) --------------
    const int sm = tid >> 4;          // row within group 0..15
    const int sd = tid & 15;          // 4-float chunk 0..15
    {
    }
    const int srow = g * 16 + sm;
    const int sb = srow / NNROW;
    const int sn = srow - sb * NNROW;
    const size_t sbase = ((size_t)(sb * TT) * NNROW + sn) * 64 + sd * 4;

    // ---------------- elementwise thread mapping ---------------------------
    const int hcol = tid & 63;
    const int rg   = tid >> 6;        // handles rows rg*4 .. rg*4+3
    float ct[4] = {0.f, 0.f, 0.f, 0.f};
    const float bf_ = b_x[hcol];
    const float bi_ = b_x[64 + hcol];
    const float bo_ = b_x[128 + hcol];
    const float bu_ = b_x[192 + hcol];
    const float bgf = b_g[hcol];
    const float bgu = b_g[64 + hcol];
    size_t obase[4];
    int    fo[4];
    #pragma unroll
    for (int e = 0; e < 4; ++e) {
        const int m = rg * 4 + e;
        const int row = g * 16 + m;
        const int b = row / NNROW;
        const int n = row - b * NNROW;
        obase[e] = ((size_t)(b * TT) * NNROW + n) * 64 + hcol;
        fo[e]    = (b * NNROW + n) * 64 + hcol;
    }

    // zero the h section of the A-buffer (initial hidden state = 0)
    {
        short4v z = {0, 0, 0, 0};
        *(short4v*)&Abuf[sm * A_STRIDE + 128 + sd * 4] = z;
    }

    // initial prefetch (t = 0)
    float4 xq = *(const float4*)(x + sbase);
    float4 oq = *(const float4*)(o_s + sbase);

    for (int t = 0; t < TT; ++t) {
        // ---- stage current x/os tile into LDS (bf16) ----
        {
            short4v sx = { f2bf(xq.x), f2bf(xq.y), f2bf(xq.z), f2bf(xq.w) };
            short4v so = { f2bf(oq.x), f2bf(oq.y), f2bf(oq.z), f2bf(oq.w) };
            *(short4v*)&Abuf[sm * A_STRIDE + sd * 4]      = sx;
            *(short4v*)&Abuf[sm * A_STRIDE + 64 + sd * 4] = so;
        }
        // ---- prefetch next step while this step computes ----
        {
            const int tn = (t < TT - 1) ? t + 1 : t;
            xq = *(const float4*)(x + sbase + (size_t)tn * STEP_OFS);
            oq = *(const float4*)(o_s + sbase + (size_t)tn * STEP_OFS);
        }
        __syncthreads();

        // ---- MFMA phase: gates(16x256) and gov(16x128) ----
        {
            const short* Ab = &Abuf[ln * A_STRIDE + q * 8];
            const short8 ax0 = *(const short8*)(Ab + 0);
            const short8 ax1 = *(const short8*)(Ab + 32);
            const short8 ao0 = *(const short8*)(Ab + 64);
            const short8 ao1 = *(const short8*)(Ab + 96);
            const short8 ah0 = *(const short8*)(Ab + 128);
            const short8 ah1 = *(const short8*)(Ab + 160);
            #pragma unroll
            for (int nt = 0; nt < 4; ++nt) {
                f32x4 acc = {0.f, 0.f, 0.f, 0.f};
                acc = __builtin_amdgcn_mfma_f32_16x16x32_bf16(ax0, frW[nt][0], acc, 0, 0, 0);
                acc = __builtin_amdgcn_mfma_f32_16x16x32_bf16(ax1, frW[nt][1], acc, 0, 0, 0);
                acc = __builtin_amdgcn_mfma_f32_16x16x32_bf16(ah0, frW[nt][2], acc, 0, 0, 0);
                acc = __builtin_amdgcn_mfma_f32_16x16x32_bf16(ah1, frW[nt][3], acc, 0, 0, 0);
                const int col = w * 64 + nt * 16 + ln;
                #pragma unroll
                for (int r = 0; r < 4; ++r)
                    Gbuf[col * G_STRIDE + q * 4 + r] = acc[r];
            }
            #pragma unroll
            for (int nt = 0; nt < 2; ++nt) {
                f32x4 acc = {0.f, 0.f, 0.f, 0.f};
                acc = __builtin_amdgcn_mfma_f32_16x16x32_bf16(ao0, frG[nt][0], acc, 0, 0, 0);
                acc = __builtin_amdgcn_mfma_f32_16x16x32_bf16(ao1, frG[nt][1], acc, 0, 0, 0);
                acc = __builtin_amdgcn_mfma_f32_16x16x32_bf16(ah0, frG[nt][2], acc, 0, 0, 0);
                acc = __builtin_amdgcn_mfma_f32_16x16x32_bf16(ah1, frG[nt][3], acc, 0, 0, 0);
                const int col = 256 + w * 32 + nt * 16 + ln;
                #pragma unroll
                for (int r = 0; r < 4; ++r)
                    Gbuf[col * G_STRIDE + q * 4 + r] = acc[r];
            }
        }
        __syncthreads();

        // ---- elementwise: cell update, h store ----
        {
            const size_t tofs = (size_t)t * STEP_OFS;
            #pragma unroll
            for (int e = 0; e < 4; ++e) {
                const int m = rg * 4 + e;
                float f  = Gbuf[(hcol      ) * G_STRIDE + m] + bf_;
                float ii = Gbuf[( 64 + hcol) * G_STRIDE + m] + bi_;
                float oo = Gbuf[(128 + hcol) * G_STRIDE + m] + bo_;
                float uu = Gbuf[(192 + hcol) * G_STRIDE + m] + bu_;
                float gf = Gbuf[(256 + hcol) * G_STRIDE + m] + bgf;
                float gu = Gbuf[(320 + hcol) * G_STRIDE + m] + bgu;
                float c = fsig(gf) * fsig(f) * ct[e] + fsig(gu) * fsig(ii) * fsig(uu);
                ct[e] = c;
                float h = fsig(oo) * ftanh_fast(c);
                out[obase[e] + tofs] = h;
                Abuf[m * A_STRIDE + 128 + hcol] = f2bf(h);
                if (t == TT - 1) {
                    out[HT_OFS + fo[e]] = h;
                    out[CT_OFS + fo[e]] = c;
                }
            }
        }
        __syncthreads();
    }
}

extern "C" void kernel_launch(void* const* d_in, const int* in_sizes, int n_in,
                              void* d_out, int out_size, void* d_ws, size_t ws_size,
                              hipStream_t stream) {
    const float* x   = (const float*)d_in[0];
    const float* o_s = (const float*)d_in[1];
    const float* U_x = (const float*)d_in[2];
    const float* V_x = (const float*)d_in[3];
    const float* b_x = (const float*)d_in[4];
    const float* U_g = (const float*)d_in[5];
    const float* V_g = (const float*)d_in[6];
    const float* b_g = (const float*)d_in[7];
    float* out = (float*)d_out;

    glstm_kernel<<<dim3(325), dim3(256), 0, stream>>>(x, o_s, U_x, V_x, b_x, U_g, V_g, b_g, out);
}

// Round 2
// 365.810 us; speedup vs baseline: 1.2857x; 1.2857x over previous
//
#include <hip/hip_runtime.h>
#include <stdint.h>

// GLSTM: B=16, T=96, N=325, D=64, H=64.
// 5200 independent rows (b,n), each a 96-step recurrence.
// One block (256 thr) per 16-row group; weights live in registers as MFMA
// B-fragments; bf16 MFMA (fp32 acc) for the two per-step matmuls.
//
// R2: barriers are raw `s_waitcnt lgkmcnt(0); s_barrier` (never vmcnt) so the
// per-step x/o_s prefetch and the h-store stay in flight across barriers;
// 3 barriers -> 2; prefetch depth 2 (t-loop unrolled by 2); v_rcp_f32 instead
// of IEEE divides in sigmoid/tanh; Gbuf round-trip via ds_*_b128 (stride 20).

#define TT 96
#define NNROW 325
#define STEP_OFS 20800          // N*H floats per time step
#define HT_OFS 31948800
#define CT_OFS 32281600

typedef __attribute__((ext_vector_type(8))) short short8;
typedef __attribute__((ext_vector_type(4))) short short4v;
typedef __attribute__((ext_vector_type(4))) float f32x4;

#define A_STRIDE 200   // shorts per A-row: [x(64)|os(64)|h(64)|pad(8)]
#define G_STRIDE 20    // floats per gate column (16 rows + 4 pad; 80B, 16B-aligned)

// barrier that does NOT drain vmcnt (prefetch loads / global stores stay in flight)
#define BAR() asm volatile("s_waitcnt lgkmcnt(0)\n\ts_barrier" ::: "memory")

__device__ __forceinline__ short f2bf(float f) {
    union { float f; uint32_t u; } v; v.f = f;
    uint32_t r = (v.u + 0x7FFFu + ((v.u >> 16) & 1u)) >> 16;
    return (short)(r & 0xFFFFu);
}
__device__ __forceinline__ float frcp(float x) { return __builtin_amdgcn_rcpf(x); }
__device__ __forceinline__ float fsig(float x) { return frcp(1.0f + __expf(-x)); }
__device__ __forceinline__ float ftanh_fast(float x) {
    return 1.0f - 2.0f * frcp(__expf(2.0f * x) + 1.0f);
}

__global__ __launch_bounds__(256, 2)
void glstm_kernel(const float* __restrict__ x,
                  const float* __restrict__ o_s,
                  const float* __restrict__ U_x,
                  const float* __restrict__ V_x,
                  const float* __restrict__ b_x,
                  const float* __restrict__ U_g,
                  const float* __restrict__ V_g,
                  const float* __restrict__ b_g,
                  float* __restrict__ out)
{
    __shared__ __align__(16) short Abuf[16 * A_STRIDE];   // 6.4 KB
    __shared__ __align__(16) float Gbuf[384 * G_STRIDE];  // 30.7 KB

    const int tid  = threadIdx.x;
    const int g    = blockIdx.x;      // row-group 0..324
    const int lane = tid & 63;
    const int w    = tid >> 6;        // wave 0..3
    const int q    = lane >> 4;       // quad 0..3 (k-group)
    const int ln   = lane & 15;       // n / m index within tile

    // ---------------- one-time: weight B-fragments into registers ----------
    short8 frW[4][4];
    short8 frG[2][4];
    #pragma unroll
    for (int nt = 0; nt < 4; ++nt) {
        const int col = w * 64 + nt * 16 + ln;
        #pragma unroll
        for (int kb = 0; kb < 4; ++kb) {
            const float* Wp = (kb < 2) ? (U_x + (size_t)(kb * 32 + q * 8) * 256 + col)
                                       : (V_x + (size_t)((kb - 2) * 32 + q * 8) * 256 + col);
            short8 fr;
            #pragma unroll
            for (int j = 0; j < 8; ++j) fr[j] = f2bf(Wp[(size_t)j * 256]);
            frW[nt][kb] = fr;
        }
    }
    #pragma unroll
    for (int nt = 0; nt < 2; ++nt) {
        const int col = w * 32 + nt * 16 + ln;
        #pragma unroll
        for (int kb = 0; kb < 4; ++kb) {
            const float* Wp = (kb < 2) ? (U_g + (size_t)(kb * 32 + q * 8) * 128 + col)
                                       : (V_g + (size_t)((kb - 2) * 32 + q * 8) * 128 + col);
            short8 fr;
            #pragma unroll
            for (int j = 0; j < 8; ++j) fr[j] = f2bf(Wp[(size_t)j * 128]);
            frG[nt][kb] = fr;
        }
    }

    // ---------------- staging mapping (x / o_s -> LDS) ----------------------
    const int sm = tid >> 4;          // row within group 0..15
    const int sd = tid & 15;          // 4-float chunk 0..15
    const int srow = g * 16 + sm;
    const int sb = srow / NNROW;
    const int sn = srow - sb * NNROW;
    const size_t sbase = ((size_t)(sb * TT) * NNROW + sn) * 64 + sd * 4;

    // ---------------- elementwise mapping -----------------------------------
    const int hcol = tid & 63;
    const int rg   = tid >> 6;        // handles rows rg*4 .. rg*4+3
    float ct[4] = {0.f, 0.f, 0.f, 0.f};
    const float bf_ = b_x[hcol];
    const float bi_ = b_x[64 + hcol];
    const float bo_ = b_x[128 + hcol];
    const float bu_ = b_x[192 + hcol];
    const float bgf = b_g[hcol];
    const float bgu = b_g[64 + hcol];
    size_t obase[4];
    int    fo[4];
    #pragma unroll
    for (int e = 0; e < 4; ++e) {
        const int m = rg * 4 + e;
        const int row = g * 16 + m;
        const int b = row / NNROW;
        const int n = row - b * NNROW;
        obase[e] = ((size_t)(b * TT) * NNROW + n) * 64 + hcol;
        fo[e]    = (b * NNROW + n) * 64 + hcol;
    }

    // zero the h section of the A-buffer (initial hidden state = 0)
    {
        short4v z = {0, 0, 0, 0};
        *(short4v*)&Abuf[sm * A_STRIDE + 128 + sd * 4] = z;
    }

    // 2-deep prefetch
    float4 xqA = *(const float4*)(x   + sbase);
    float4 oqA = *(const float4*)(o_s + sbase);
    float4 xqB = *(const float4*)(x   + sbase + (size_t)STEP_OFS);
    float4 oqB = *(const float4*)(o_s + sbase + (size_t)STEP_OFS);

    auto step = [&](int t, float4& xq, float4& oq) {
        // ---- stage current x/os tile into LDS (bf16) ----
        {
            short4v sx = { f2bf(xq.x), f2bf(xq.y), f2bf(xq.z), f2bf(xq.w) };
            short4v so = { f2bf(oq.x), f2bf(oq.y), f2bf(oq.z), f2bf(oq.w) };
            *(short4v*)&Abuf[sm * A_STRIDE + sd * 4]      = sx;
            *(short4v*)&Abuf[sm * A_STRIDE + 64 + sd * 4] = so;
        }
        // ---- prefetch t+2 (consumed two steps from now) ----
        {
            int tn = t + 2; if (tn > TT - 1) tn = TT - 1;
            xq = *(const float4*)(x   + sbase + (size_t)tn * STEP_OFS);
            oq = *(const float4*)(o_s + sbase + (size_t)tn * STEP_OFS);
        }
        BAR();  // h(t-1) + x/os(t) visible -> MFMA may read

        // ---- MFMA phase: gates(16x256) and gov(16x128) ----
        {
            const short* Ab = &Abuf[ln * A_STRIDE + q * 8];
            const short8 ax0 = *(const short8*)(Ab + 0);
            const short8 ax1 = *(const short8*)(Ab + 32);
            const short8 ao0 = *(const short8*)(Ab + 64);
            const short8 ao1 = *(const short8*)(Ab + 96);
            const short8 ah0 = *(const short8*)(Ab + 128);
            const short8 ah1 = *(const short8*)(Ab + 160);
            #pragma unroll
            for (int nt = 0; nt < 4; ++nt) {
                f32x4 acc = {0.f, 0.f, 0.f, 0.f};
                acc = __builtin_amdgcn_mfma_f32_16x16x32_bf16(ax0, frW[nt][0], acc, 0, 0, 0);
                acc = __builtin_amdgcn_mfma_f32_16x16x32_bf16(ax1, frW[nt][1], acc, 0, 0, 0);
                acc = __builtin_amdgcn_mfma_f32_16x16x32_bf16(ah0, frW[nt][2], acc, 0, 0, 0);
                acc = __builtin_amdgcn_mfma_f32_16x16x32_bf16(ah1, frW[nt][3], acc, 0, 0, 0);
                const int col = w * 64 + nt * 16 + ln;
                *(f32x4*)&Gbuf[col * G_STRIDE + q * 4] = acc;   // ds_write_b128
            }
            #pragma unroll
            for (int nt = 0; nt < 2; ++nt) {
                f32x4 acc = {0.f, 0.f, 0.f, 0.f};
                acc = __builtin_amdgcn_mfma_f32_16x16x32_bf16(ao0, frG[nt][0], acc, 0, 0, 0);
                acc = __builtin_amdgcn_mfma_f32_16x16x32_bf16(ao1, frG[nt][1], acc, 0, 0, 0);
                acc = __builtin_amdgcn_mfma_f32_16x16x32_bf16(ah0, frG[nt][2], acc, 0, 0, 0);
                acc = __builtin_amdgcn_mfma_f32_16x16x32_bf16(ah1, frG[nt][3], acc, 0, 0, 0);
                const int col = 256 + w * 32 + nt * 16 + ln;
                *(f32x4*)&Gbuf[col * G_STRIDE + q * 4] = acc;   // ds_write_b128
            }
        }
        BAR();  // Gbuf(t) visible -> elementwise may read; x/os region reusable

        // ---- elementwise: cell update, h store ----
        {
            const f32x4 vf = *(const f32x4*)&Gbuf[(hcol      ) * G_STRIDE + rg * 4];
            const f32x4 vi = *(const f32x4*)&Gbuf[( 64 + hcol) * G_STRIDE + rg * 4];
            const f32x4 vo = *(const f32x4*)&Gbuf[(128 + hcol) * G_STRIDE + rg * 4];
            const f32x4 vu = *(const f32x4*)&Gbuf[(192 + hcol) * G_STRIDE + rg * 4];
            const f32x4 vgf = *(const f32x4*)&Gbuf[(256 + hcol) * G_STRIDE + rg * 4];
            const f32x4 vgu = *(const f32x4*)&Gbuf[(320 + hcol) * G_STRIDE + rg * 4];
            const size_t tofs = (size_t)t * STEP_OFS;
            #pragma unroll
            for (int e = 0; e < 4; ++e) {
                const int m = rg * 4 + e;
                float c = fsig(vgf[e] + bgf) * fsig(vf[e] + bf_) * ct[e]
                        + fsig(vgu[e] + bgu) * fsig(vi[e] + bi_) * fsig(vu[e] + bu_);
                ct[e] = c;
                float h = fsig(vo[e] + bo_) * ftanh_fast(c);
                out[obase[e] + tofs] = h;
                Abuf[m * A_STRIDE + 128 + hcol] = f2bf(h);
                if (t == TT - 1) {
                    out[HT_OFS + fo[e]] = h;
                    out[CT_OFS + fo[e]] = c;
                }
            }
        }
        // no third barrier: stage(t+1) writes x/os region (disjoint from h),
        // and Gbuf(t+1) writes are ordered behind BAR() #1 of the next step.
    };

    for (int t = 0; t < TT; t += 2) {
        step(t,     xqA, oqA);
        step(t + 1, xqB, oqB);
    }
}

extern "C" void kernel_launch(void* const* d_in, const int* in_sizes, int n_in,
                              void* d_out, int out_size, void* d_ws, size_t ws_size,
                              hipStream_t stream) {
    const float* x   = (const float*)d_in[0];
    const float* o_s = (const float*)d_in[1];
    const float* U_x = (const float*)d_in[2];
    const float* V_x = (const float*)d_in[3];
    const float* b_x = (const float*)d_in[4];
    const float* V_g = (const float*)d_in[6];
    const float* U_g = (const float*)d_in[5];
    const float* b_g = (const float*)d_in[7];
    float* out = (float*)d_out;

    glstm_kernel<<<dim3(325), dim3(256), 0, stream>>>(x, o_s, U_x, V_x, b_x, U_g, V_g, b_g, out);
}